// Round 5
// baseline (675.602 us; speedup 1.0000x reference)
//
#include <hip/hip_runtime.h>

typedef __attribute__((ext_vector_type(8))) short short8;
typedef __attribute__((ext_vector_type(4))) float float4_t;
typedef __attribute__((ext_vector_type(4))) unsigned short ushort4_t;

#define NR 8192
#define C 128
#define SPLITK 4
#define KCHUNK (NR / SPLITK)   // 2048
#define BK 64
#define STEPS (KCHUNK / BK)    // 32

// Static device scratch (fully rewritten each call; no reliance on ws_size).
__device__ unsigned short g_Lb[(size_t)NR * NR];    // packed bf16 L: [mb][kq][r][8] (128 MB)
__device__ unsigned short g_xbT[(size_t)C * NR];    // xbT[c][n] = bf16(x[n][c])
__device__ unsigned short g_T1b[(size_t)NR * C];    // row-major bf16 T1
__device__ unsigned short g_T1bT[(size_t)C * NR];   // T1bT[c][n] = bf16(T1[n][c])
__device__ unsigned short g_Wb[3 * C * C];          // bf16 W
__device__ float g_part[(size_t)SPLITK * NR * C];   // split-K partials (16 MB)
__device__ int g_cnt[2][128];                       // split-K arrival counters

__device__ __forceinline__ unsigned short f2bf(float f) {
  union { float f; unsigned u; } v; v.f = f;
  unsigned r = v.u + 0x7fffu + ((v.u >> 16) & 1u);  // RNE
  return (unsigned short)(r >> 16);
}
__device__ __forceinline__ unsigned pk2(float a, float b) {
  union { float f; unsigned u; } x, y; x.f = a; y.f = b;
  unsigned ra = x.u + 0x7fffu + ((x.u >> 16) & 1u);
  unsigned rb = y.u + 0x7fffu + ((y.u >> 16) & 1u);
  return (ra >> 16) | (rb & 0xffff0000u);
}
__device__ __forceinline__ short8 cvt8(float4_t f0, float4_t f1) {
  union { unsigned u[4]; short8 s; } r;
  r.u[0] = pk2(f0[0], f0[1]); r.u[1] = pk2(f0[2], f0[3]);
  r.u[2] = pk2(f1[0], f1[1]); r.u[3] = pk2(f1[2], f1[3]);
  return r.s;
}

typedef __attribute__((address_space(3))) unsigned lds_uint;
typedef const __attribute__((address_space(1))) unsigned glob_uint;
__device__ __forceinline__ void gload_lds16(const void* g, void* l) {
  __builtin_amdgcn_global_load_lds((glob_uint*)g, (lds_uint*)l, 16, 0, 0);
}

// ---- tiny: W fp32 -> bf16, plus zero the split-K counters -------------------
__global__ void cvt_w(const float* __restrict__ W) {
  if (blockIdx.x == 0) ((int*)g_cnt)[threadIdx.x] = 0;   // 2*128 = 256 ints
  int i = (blockIdx.x * 256 + threadIdx.x) * 4;
  float4_t v = *(const float4_t*)(W + i);
  ushort4_t h; h[0]=f2bf(v[0]); h[1]=f2bf(v[1]); h[2]=f2bf(v[2]); h[3]=f2bf(v[3]);
  *(ushort4_t*)(g_Wb + i) = h;
}

// ---- pack L: fp32 row-major -> bf16 [mb][kq][r][8] --------------------------
// Block (mb, y): rows mb*64..+63, cols y*512..+511. Reads are full-width row
// segments (2 KB per row visit -> page-friendly); writes are one contiguous
// 64 KB run per block. Same RNE conversion as the in-register cvt8, so gemm
// numerics are bit-identical to the previously verified kernel.
__global__ __launch_bounds__(256) void pack_l(const float* __restrict__ L) {
  __shared__ __attribute__((aligned(16))) unsigned short tile[64][520];
  int mb = blockIdx.x;   // 0..127
  int y  = blockIdx.y;   // 0..15
  int t = threadIdx.x;
#pragma unroll
  for (int it = 0; it < 32; it++) {
    int idx = it * 256 + t;        // f4 index 0..8191
    int row = idx >> 7;            // local row 0..63
    int c4  = idx & 127;           // f4 within row
    float4_t v = *(const float4_t*)(L + (size_t)(mb * 64 + row) * NR + y * 512 + c4 * 4);
    ushort4_t h; h[0]=f2bf(v[0]); h[1]=f2bf(v[1]); h[2]=f2bf(v[2]); h[3]=f2bf(v[3]);
    *(ushort4_t*)(&tile[row][c4 * 4]) = h;
  }
  __syncthreads();
  // unit u = kql*64 + r  (kql = local kq 0..63, r = local row 0..63)
  unsigned short* dst = g_Lb + (size_t)(mb * 1024 + y * 64) * 512;  // *64 rows *8 elems
#pragma unroll
  for (int j = 0; j < 16; j++) {
    int u = j * 256 + t;
    int kql = u >> 6, r = u & 63;
    short8 h = *(const short8*)(&tile[r][kql * 8]);   // contiguous 16B in LDS row
    *(short8*)(dst + (size_t)u * 8) = h;              // per-wave contiguous 1KB
  }
}

// ---- x [8192][128] fp32 -> xbT [128][8192] bf16 -----------------------------
__global__ void transpose_x(const float* __restrict__ x) {
  __shared__ unsigned short xt[64][72];
  int r0 = blockIdx.x * 64;
  int c0 = blockIdx.y * 64;
  int t = threadIdx.x;
  int rr = t >> 4;
  int cc = (t & 15) * 4;
#pragma unroll
  for (int i = 0; i < 4; i++) {
    int row = i * 16 + rr;
    float4_t v = *(const float4_t*)(x + (size_t)(r0 + row) * C + c0 + cc);
    ushort4_t h; h[0]=f2bf(v[0]); h[1]=f2bf(v[1]); h[2]=f2bf(v[2]); h[3]=f2bf(v[3]);
    *(ushort4_t*)(&xt[row][cc]) = h;
  }
  __syncthreads();
  int c = t >> 2, q = t & 3;   // c 0..63, q: 16-row group
  unsigned short* dst = g_xbT + (size_t)(c0 + c) * NR + r0 + q * 16;
#pragma unroll
  for (int seg = 0; seg < 2; seg++) {
    short8 h;
#pragma unroll
    for (int j = 0; j < 8; j++) h[j] = (short)xt[q * 16 + seg * 8 + j][c];
    *(short8*)(dst + seg * 8) = h;   // 16B stores
  }
}

// ---- GEMM: part = Lb(bf16 packed) @ B ; BM=64, BN=128, BK=64 ----------------
// A source is the packed layout: each step's 8 KB A-tile is one contiguous
// burst; a block's whole K-chunk is a contiguous 256 KB stream.
// Double-buffered LDS, raw s_barrier + fine-grained vmcnt.
// which==0: BT=g_xbT, finisher produces T1b/T1bT.
// which==1: BT=g_T1bT, finisher does T2 = 2U - x and the three W-GEMMs -> out.
// Split-K finisher handshake: stores -> __threadfence (each thread) ->
// __syncthreads -> tid0 atomicAdd. The syncthreads between the fences and the
// atomic is what makes every thread's stores visible before the counter bump.
__global__ __launch_bounds__(256, 2) void gemm_cheb(int which,
                                                    const float* __restrict__ x,
                                                    float* __restrict__ out) {
  const unsigned short* __restrict__ BT = which ? g_T1bT : g_xbT;
  __shared__ __attribute__((aligned(16))) unsigned short As[2][64 * BK];   // 2x8 KB
  __shared__ __attribute__((aligned(16))) unsigned short Bs[2][128 * BK];  // 2x16 KB
  __shared__ int s_rank;
  int tid = threadIdx.x;
  int wave = tid >> 6, lane = tid & 63;
  int l15 = lane & 15, lq = lane >> 4;
  int m0 = blockIdx.x * 64;
  int kb = blockIdx.y * KCHUNK;

  // A staging: 8 KB/step = 512 units of 16B; unit = kq_local*64 + r.
  const unsigned short* pA[2];
  size_t abase = (size_t)(blockIdx.x * 1024 + blockIdx.y * (KCHUNK / 8)) * 512;
#pragma unroll
  for (int i = 0; i < 2; i++)
    pA[i] = g_Lb + abase + (size_t)((wave * 2 + i) * 64 + lane) * 8;

  // B staging: 128 n x 64 bf16 = 16KB = 8 units of 16B per row (XOR-swizzled).
  const unsigned short* pB[4];
#pragma unroll
  for (int i = 0; i < 4; i++) {
    int U = (wave * 4 + i) * 64 + lane;   // 0..1023
    int n = U >> 3, p = U & 7;
    pB[i] = BT + (size_t)n * NR + kb + ((p ^ (n & 7)) << 3);
  }

  float4_t acc[8];
#pragma unroll
  for (int ni = 0; ni < 8; ni++) acc[ni] = (float4_t){0.f, 0.f, 0.f, 0.f};

  #define ISSUE(buf)                                                         \
    do {                                                                     \
      _Pragma("unroll")                                                      \
      for (int i = 0; i < 2; i++)                                            \
        gload_lds16(pA[i], (char*)&As[buf][0] + (wave * 2 + i) * 1024);      \
      _Pragma("unroll")                                                      \
      for (int i = 0; i < 4; i++)                                            \
        gload_lds16(pB[i], (char*)&Bs[buf][0] + (wave * 4 + i) * 1024);      \
      _Pragma("unroll")                                                      \
      for (int i = 0; i < 2; i++) pA[i] += 8 * 64 * 8;                       \
      _Pragma("unroll")                                                      \
      for (int i = 0; i < 4; i++) pB[i] += BK;                               \
    } while (0)

  #define COMPUTE(buf)                                                       \
    do {                                                                     \
      _Pragma("unroll")                                                      \
      for (int ki = 0; ki < 2; ki++) {                                       \
        int row = wave * 16 + l15;                                           \
        short8 a = *(const short8*)((const char*)&As[buf][0] +               \
                                    ((((ki * 4 + lq) << 6) + row) << 4));    \
        _Pragma("unroll")                                                    \
        for (int ni = 0; ni < 8; ni++) {                                     \
          int n = ni * 16 + l15;                                             \
          int pb = ((ki << 2) | lq) ^ (n & 7);                               \
          short8 b = *(const short8*)((const char*)&Bs[buf][0] + n * 128 + pb * 16);             \
          acc[ni] = __builtin_amdgcn_mfma_f32_16x16x32_bf16(a, b, acc[ni], 0, 0, 0);             \
        }                                                                    \
      }                                                                      \
    } while (0)

  ISSUE(0);
  for (int step = 0; step < STEPS - 1; step++) {
    int p = step & 1;
    ISSUE(p ^ 1);                                        // prefetch step+1
    asm volatile("s_waitcnt vmcnt(6)" ::: "memory");     // my 6 loads for buf p done
    asm volatile("s_barrier" ::: "memory");              // everyone's are done
    COMPUTE(p);
    asm volatile("s_barrier" ::: "memory");              // buf p free to overwrite
  }
  asm volatile("s_waitcnt vmcnt(0)" ::: "memory");
  asm volatile("s_barrier" ::: "memory");
  COMPUTE((STEPS - 1) & 1);

  float* po = g_part + (size_t)blockIdx.y * NR * C;
#pragma unroll
  for (int ni = 0; ni < 8; ni++)
#pragma unroll
    for (int r = 0; r < 4; r++)
      po[(size_t)(m0 + wave * 16 + lq * 4 + r) * C + ni * 16 + l15] = acc[ni][r];
  #undef ISSUE
  #undef COMPUTE

  // ---- split-K finisher: last block for this m-block reduces partials -----
  __threadfence();                                   // release my stores (per-thread)
  __syncthreads();                                   // ALL threads' fences done
  if (tid == 0) s_rank = atomicAdd(&g_cnt[which][blockIdx.x], 1);
  __syncthreads();                                   // broadcast rank; As/Bs free
  if (s_rank != SPLITK - 1) return;
  __threadfence();                                   // acquire others' partials

  if (which == 0) {
    // T1 = sum partials -> g_T1b (row-major) + g_T1bT (transposed), 64 rows.
    unsigned short (*tile)[136] = (unsigned short (*)[136])&As[0][0];  // 4.3 KB
#pragma unroll 1
    for (int s = 0; s < 4; s++) {
      int r0 = m0 + s * 16;
#pragma unroll
      for (int e = 0; e < 2; e++) {
        int linear = e * 1024 + tid * 4;
        int r = linear >> 7, c = linear & 127;
        float4_t sum = (float4_t){0.f, 0.f, 0.f, 0.f};
#pragma unroll
        for (int p = 0; p < SPLITK; p++)
          sum += *(const float4_t*)(g_part + (size_t)p * NR * C + (size_t)(r0 + r) * C + c);
        ushort4_t h; h[0]=f2bf(sum[0]); h[1]=f2bf(sum[1]); h[2]=f2bf(sum[2]); h[3]=f2bf(sum[3]);
        *(ushort4_t*)(g_T1b + (size_t)(r0 + r) * C + c) = h;
        *(ushort4_t*)(&tile[r][c]) = h;
      }
      __syncthreads();
      int c = tid >> 1, half = tid & 1;
      short8 h;
#pragma unroll
      for (int j = 0; j < 8; j++) h[j] = (short)tile[half * 8 + j][c];
      *(short8*)(g_T1bT + (size_t)c * NR + r0 + half * 8) = h;
      __syncthreads();
    }
  } else {
    // U = sum partials; T2 = 2U - x; out = T0 W0^T + T1 W1^T + T2 W2^T.
    unsigned short (*t2)[136] = (unsigned short (*)[136])&As[0][0];  // 8.7 KB
#pragma unroll 1
    for (int s = 0; s < 2; s++) {
      int r0 = m0 + s * 32;
#pragma unroll
      for (int e = 0; e < 4; e++) {
        int linear = e * 1024 + tid * 4;
        int r = linear >> 7, c = linear & 127;
        float4_t sum = (float4_t){0.f, 0.f, 0.f, 0.f};
#pragma unroll
        for (int p = 0; p < SPLITK; p++)
          sum += *(const float4_t*)(g_part + (size_t)p * NR * C + (size_t)(r0 + r) * C + c);
        float4_t xv = *(const float4_t*)(x + (size_t)(r0 + r) * C + c);
        float4_t t2v = 2.0f * sum - xv;
        ushort4_t h; h[0]=f2bf(t2v[0]); h[1]=f2bf(t2v[1]); h[2]=f2bf(t2v[2]); h[3]=f2bf(t2v[3]);
        *(ushort4_t*)(&t2[r][c]) = h;
      }
      __syncthreads();

      int mf = wave & 1, nh = wave >> 1;
      int m0r = r0 + mf * 16;
      float4_t oacc[4];
#pragma unroll
      for (int ni = 0; ni < 4; ni++) oacc[ni] = (float4_t){0.f, 0.f, 0.f, 0.f};
#pragma unroll
      for (int ks = 0; ks < 4; ks++) {
        int k0 = ks * 32 + lq * 8;
        const float* px = x + (size_t)(m0r + l15) * C + k0;
        float4_t f0 = *(const float4_t*)px;
        float4_t f1 = *(const float4_t*)(px + 4);
        short8 a0 = cvt8(f0, f1);
        short8 a1 = *(const short8*)(g_T1b + (size_t)(m0r + l15) * C + k0);
        short8 a2 = *(const short8*)(&t2[mf * 16 + l15][k0]);
#pragma unroll
        for (int ni = 0; ni < 4; ni++) {
          int n = nh * 64 + ni * 16 + l15;
          const unsigned short* pw = g_Wb + (size_t)n * C + k0;
          short8 w0 = *(const short8*)(pw);
          short8 w1 = *(const short8*)(pw + C * C);
          short8 w2 = *(const short8*)(pw + 2 * C * C);
          oacc[ni] = __builtin_amdgcn_mfma_f32_16x16x32_bf16(a0, w0, oacc[ni], 0, 0, 0);
          oacc[ni] = __builtin_amdgcn_mfma_f32_16x16x32_bf16(a1, w1, oacc[ni], 0, 0, 0);
          oacc[ni] = __builtin_amdgcn_mfma_f32_16x16x32_bf16(a2, w2, oacc[ni], 0, 0, 0);
        }
      }
#pragma unroll
      for (int ni = 0; ni < 4; ni++)
#pragma unroll
        for (int r = 0; r < 4; r++)
          out[(size_t)(m0r + lq * 4 + r) * C + nh * 64 + ni * 16 + l15] = oacc[ni][r];
      __syncthreads();   // t2 tile free before next s
    }
  }
}

extern "C" void kernel_launch(void* const* d_in, const int* in_sizes, int n_in,
                              void* d_out, int out_size, void* d_ws, size_t ws_size,
                              hipStream_t stream) {
  const float* x = (const float*)d_in[0];   // [8192][128]
  const float* L = (const float*)d_in[1];   // [8192][8192]
  const float* W = (const float*)d_in[2];   // [3][128][128]
  float* out = (float*)d_out;               // [8192][128]

  cvt_w<<<48, 256, 0, stream>>>(W);                         // + zero counters
  transpose_x<<<dim3(128, 2), 256, 0, stream>>>(x);
  pack_l<<<dim3(128, 16), 256, 0, stream>>>(L);             // L -> bf16 packed
  gemm_cheb<<<dim3(128, SPLITK), 256, 0, stream>>>(0, x, out);  // T1 + fused reduce
  gemm_cheb<<<dim3(128, SPLITK), 256, 0, stream>>>(1, x, out);  // U + fused epilogue
}

// Round 6
// 498.227 us; speedup vs baseline: 1.3560x; 1.3560x over previous
//
#include <hip/hip_runtime.h>

typedef __attribute__((ext_vector_type(8))) short short8;
typedef __attribute__((ext_vector_type(4))) float float4_t;
typedef __attribute__((ext_vector_type(4))) unsigned short ushort4_t;

#define NR 8192
#define C 128
#define SPLITK 4
#define KCHUNK (NR / SPLITK)   // 2048
#define BK 64
#define STEPS (KCHUNK / BK)    // 32

// Static device scratch (fully rewritten each call; no reliance on ws_size).
__device__ unsigned short g_Lb[(size_t)NR * NR];    // packed bf16 L: [mb][kq][r][8] (128 MB)
__device__ unsigned short g_xbT[(size_t)C * NR];    // xbT[c][n] = bf16(x[n][c])
__device__ unsigned short g_T1b[(size_t)NR * C];    // row-major bf16 T1
__device__ unsigned short g_T1bT[(size_t)C * NR];   // T1bT[c][n] = bf16(T1[n][c])
__device__ unsigned short g_Wb[3 * C * C];          // bf16 W
__device__ float g_part[(size_t)SPLITK * NR * C];   // split-K partials (16 MB)

__device__ __forceinline__ unsigned short f2bf(float f) {
  union { float f; unsigned u; } v; v.f = f;
  unsigned r = v.u + 0x7fffu + ((v.u >> 16) & 1u);  // RNE
  return (unsigned short)(r >> 16);
}
__device__ __forceinline__ unsigned pk2(float a, float b) {
  union { float f; unsigned u; } x, y; x.f = a; y.f = b;
  unsigned ra = x.u + 0x7fffu + ((x.u >> 16) & 1u);
  unsigned rb = y.u + 0x7fffu + ((y.u >> 16) & 1u);
  return (ra >> 16) | (rb & 0xffff0000u);
}
__device__ __forceinline__ short8 cvt8(float4_t f0, float4_t f1) {
  union { unsigned u[4]; short8 s; } r;
  r.u[0] = pk2(f0[0], f0[1]); r.u[1] = pk2(f0[2], f0[3]);
  r.u[2] = pk2(f1[0], f1[1]); r.u[3] = pk2(f1[2], f1[3]);
  return r.s;
}

typedef __attribute__((address_space(3))) unsigned lds_uint;
typedef const __attribute__((address_space(1))) unsigned glob_uint;
__device__ __forceinline__ void gload_lds16(const void* g, void* l) {
  __builtin_amdgcn_global_load_lds((glob_uint*)g, (lds_uint*)l, 16, 0, 0);
}

// ---- tiny: W fp32 -> bf16 ---------------------------------------------------
__global__ void cvt_w(const float* __restrict__ W) {
  int i = (blockIdx.x * 256 + threadIdx.x) * 4;
  float4_t v = *(const float4_t*)(W + i);
  ushort4_t h; h[0]=f2bf(v[0]); h[1]=f2bf(v[1]); h[2]=f2bf(v[2]); h[3]=f2bf(v[3]);
  *(ushort4_t*)(g_Wb + i) = h;
}

// ---- x [8192][128] fp32 -> xbT [128][8192] bf16 -----------------------------
__global__ void transpose_x(const float* __restrict__ x) {
  __shared__ unsigned short xt[64][72];
  int r0 = blockIdx.x * 64;
  int c0 = blockIdx.y * 64;
  int t = threadIdx.x;
  int rr = t >> 4;
  int cc = (t & 15) * 4;
#pragma unroll
  for (int i = 0; i < 4; i++) {
    int row = i * 16 + rr;
    float4_t v = *(const float4_t*)(x + (size_t)(r0 + row) * C + c0 + cc);
    ushort4_t h; h[0]=f2bf(v[0]); h[1]=f2bf(v[1]); h[2]=f2bf(v[2]); h[3]=f2bf(v[3]);
    *(ushort4_t*)(&xt[row][cc]) = h;
  }
  __syncthreads();
  int c = t >> 2, q = t & 3;   // c 0..63, q: 16-row group
  unsigned short* dst = g_xbT + (size_t)(c0 + c) * NR + r0 + q * 16;
#pragma unroll
  for (int seg = 0; seg < 2; seg++) {
    short8 h;
#pragma unroll
    for (int j = 0; j < 8; j++) h[j] = (short)xt[q * 16 + seg * 8 + j][c];
    *(short8*)(dst + seg * 8) = h;   // 16B stores
  }
}

// ---- GEMM 0: part = L(fp32, cvt in-reg) @ xbT ; BM=64, BN=128, BK=64 --------
// Also PACKS: each lane stores its just-converted bf16 A-fragment to g_Lb in
// [mb][kq][r][8] layout (each L element owned by exactly one block -> written
// once; 4x256B runs per wave). gemm_u then reads A as one contiguous stream.
// Double-buffered LDS, raw s_barrier + fine-grained vmcnt.
__global__ __launch_bounds__(256, 2) void gemm_t1(const float* __restrict__ L) {
  __shared__ __attribute__((aligned(16))) float          As[2][64 * BK];   // 2x16 KB
  __shared__ __attribute__((aligned(16))) unsigned short Bs[2][128 * BK];  // 2x16 KB
  int tid = threadIdx.x;
  int wave = tid >> 6, lane = tid & 63;
  int l15 = lane & 15, lq = lane >> 4;
  int m0 = blockIdx.x * 64;
  int kb = blockIdx.y * KCHUNK;

  // A staging: 64 rows x 64 fp32 = 16KB = 16 units of 16B per row.
  // physical unit p holds logical unit (p ^ (row&15)) -> conflict-free frags.
  const float* pA[4];
#pragma unroll
  for (int i = 0; i < 4; i++) {
    int U = (wave * 4 + i) * 64 + lane;   // 0..1023
    int row = U >> 4, p = U & 15;
    pA[i] = L + (size_t)(m0 + row) * NR + kb + ((p ^ (row & 15)) << 2);
  }
  // B staging: 128 n x 64 bf16 = 16KB = 8 units of 16B per row (XOR-swizzled).
  const unsigned short* pB[4];
#pragma unroll
  for (int i = 0; i < 4; i++) {
    int U = (wave * 4 + i) * 64 + lane;   // 0..1023
    int n = U >> 3, p = U & 7;
    pB[i] = g_xbT + (size_t)n * NR + kb + ((p ^ (n & 7)) << 3);
  }
  // Pack-store base: unit = (mb*1024 + kq)*64 + row, 8 shorts per unit.
  // kq for this lane at (step, ki): kb/8 + step*8 + ki*4 + lq.
  unsigned short* pS = g_Lb +
      (((size_t)blockIdx.x * 1024 + blockIdx.y * (KCHUNK / 8) + lq) * 64 +
       wave * 16 + l15) * 8;

  float4_t acc[8];
#pragma unroll
  for (int ni = 0; ni < 8; ni++) acc[ni] = (float4_t){0.f, 0.f, 0.f, 0.f};

  #define ISSUE(buf)                                                         \
    do {                                                                     \
      _Pragma("unroll")                                                      \
      for (int i = 0; i < 4; i++)                                            \
        gload_lds16(pA[i], (char*)&As[buf][0] + (wave * 4 + i) * 1024);      \
      _Pragma("unroll")                                                      \
      for (int i = 0; i < 4; i++)                                            \
        gload_lds16(pB[i], (char*)&Bs[buf][0] + (wave * 4 + i) * 1024);      \
      _Pragma("unroll")                                                      \
      for (int i = 0; i < 4; i++) { pA[i] += BK; pB[i] += BK; }              \
    } while (0)

  #define COMPUTE(buf, stepv)                                                \
    do {                                                                     \
      _Pragma("unroll")                                                      \
      for (int ki = 0; ki < 2; ki++) {                                       \
        int row = wave * 16 + l15;                                           \
        int u0 = (ki << 3) | (lq << 1);                                      \
        int p0 = u0 ^ (row & 15);                                            \
        float4_t f0 = *(const float4_t*)((const char*)&As[buf][0] + row * 256 + p0 * 16);        \
        float4_t f1 = *(const float4_t*)((const char*)&As[buf][0] + row * 256 + (p0 ^ 1) * 16);  \
        short8 a = cvt8(f0, f1);                                             \
        *(short8*)(pS + (size_t)(stepv) * 4096 + ki * 2048) = a;             \
        _Pragma("unroll")                                                    \
        for (int ni = 0; ni < 8; ni++) {                                     \
          int n = ni * 16 + l15;                                             \
          int pb = ((ki << 2) | lq) ^ (n & 7);                               \
          short8 b = *(const short8*)((const char*)&Bs[buf][0] + n * 128 + pb * 16);             \
          acc[ni] = __builtin_amdgcn_mfma_f32_16x16x32_bf16(a, b, acc[ni], 0, 0, 0);             \
        }                                                                    \
      }                                                                      \
    } while (0)

  ISSUE(0);
  for (int step = 0; step < STEPS - 1; step++) {
    int p = step & 1;
    ISSUE(p ^ 1);                                        // prefetch step+1
    // 8 loads for buf p are the oldest outstanding vmem ops; the 2 pack
    // stores from COMPUTE(p-1) are >1 barrier old and already retired.
    asm volatile("s_waitcnt vmcnt(8)" ::: "memory");
    asm volatile("s_barrier" ::: "memory");              // everyone's are done
    COMPUTE(p, step);
    asm volatile("s_barrier" ::: "memory");              // buf p free to overwrite
  }
  asm volatile("s_waitcnt vmcnt(0)" ::: "memory");
  asm volatile("s_barrier" ::: "memory");
  COMPUTE((STEPS - 1) & 1, STEPS - 1);

  float* po = g_part + (size_t)blockIdx.y * NR * C;
#pragma unroll
  for (int ni = 0; ni < 8; ni++)
#pragma unroll
    for (int r = 0; r < 4; r++)
      po[(size_t)(m0 + wave * 16 + lq * 4 + r) * C + ni * 16 + l15] = acc[ni][r];
  #undef ISSUE
  #undef COMPUTE
}

// ---- GEMM 1: part = Lb(bf16 packed) @ T1bT ; BM=64, BN=128, BK=64 -----------
// A is the packed layout: each step's 8 KB A-tile is one contiguous burst;
// a block's whole K-chunk is a contiguous 256 KB stream.
__global__ __launch_bounds__(256, 2) void gemm_u() {
  __shared__ __attribute__((aligned(16))) unsigned short As[2][64 * BK];   // 2x8 KB
  __shared__ __attribute__((aligned(16))) unsigned short Bs[2][128 * BK];  // 2x16 KB
  int tid = threadIdx.x;
  int wave = tid >> 6, lane = tid & 63;
  int l15 = lane & 15, lq = lane >> 4;
  int m0 = blockIdx.x * 64;
  int kb = blockIdx.y * KCHUNK;

  // A staging: 8 KB/step = 512 units of 16B; unit = kq_local*64 + r.
  const unsigned short* pA[2];
  size_t abase = (size_t)(blockIdx.x * 1024 + blockIdx.y * (KCHUNK / 8)) * 512;
#pragma unroll
  for (int i = 0; i < 2; i++)
    pA[i] = g_Lb + abase + (size_t)((wave * 2 + i) * 64 + lane) * 8;

  // B staging: 128 n x 64 bf16 = 16KB = 8 units of 16B per row (XOR-swizzled).
  const unsigned short* pB[4];
#pragma unroll
  for (int i = 0; i < 4; i++) {
    int U = (wave * 4 + i) * 64 + lane;   // 0..1023
    int n = U >> 3, p = U & 7;
    pB[i] = g_T1bT + (size_t)n * NR + kb + ((p ^ (n & 7)) << 3);
  }

  float4_t acc[8];
#pragma unroll
  for (int ni = 0; ni < 8; ni++) acc[ni] = (float4_t){0.f, 0.f, 0.f, 0.f};

  #define ISSUE(buf)                                                         \
    do {                                                                     \
      _Pragma("unroll")                                                      \
      for (int i = 0; i < 2; i++)                                            \
        gload_lds16(pA[i], (char*)&As[buf][0] + (wave * 2 + i) * 1024);      \
      _Pragma("unroll")                                                      \
      for (int i = 0; i < 4; i++)                                            \
        gload_lds16(pB[i], (char*)&Bs[buf][0] + (wave * 4 + i) * 1024);      \
      _Pragma("unroll")                                                      \
      for (int i = 0; i < 2; i++) pA[i] += 8 * 64 * 8;                       \
      _Pragma("unroll")                                                      \
      for (int i = 0; i < 4; i++) pB[i] += BK;                               \
    } while (0)

  #define COMPUTE(buf)                                                       \
    do {                                                                     \
      _Pragma("unroll")                                                      \
      for (int ki = 0; ki < 2; ki++) {                                       \
        int row = wave * 16 + l15;                                           \
        short8 a = *(const short8*)((const char*)&As[buf][0] +               \
                                    ((((ki * 4 + lq) << 6) + row) << 4));    \
        _Pragma("unroll")                                                    \
        for (int ni = 0; ni < 8; ni++) {                                     \
          int n = ni * 16 + l15;                                             \
          int pb = ((ki << 2) | lq) ^ (n & 7);                               \
          short8 b = *(const short8*)((const char*)&Bs[buf][0] + n * 128 + pb * 16);             \
          acc[ni] = __builtin_amdgcn_mfma_f32_16x16x32_bf16(a, b, acc[ni], 0, 0, 0);             \
        }                                                                    \
      }                                                                      \
    } while (0)

  ISSUE(0);
  for (int step = 0; step < STEPS - 1; step++) {
    int p = step & 1;
    ISSUE(p ^ 1);                                        // prefetch step+1
    asm volatile("s_waitcnt vmcnt(6)" ::: "memory");     // my 6 loads for buf p done
    asm volatile("s_barrier" ::: "memory");              // everyone's are done
    COMPUTE(p);
    asm volatile("s_barrier" ::: "memory");              // buf p free to overwrite
  }
  asm volatile("s_waitcnt vmcnt(0)" ::: "memory");
  asm volatile("s_barrier" ::: "memory");
  COMPUTE((STEPS - 1) & 1);

  float* po = g_part + (size_t)blockIdx.y * NR * C;
#pragma unroll
  for (int ni = 0; ni < 8; ni++)
#pragma unroll
    for (int r = 0; r < 4; r++)
      po[(size_t)(m0 + wave * 16 + lq * 4 + r) * C + ni * 16 + l15] = acc[ni][r];
  #undef ISSUE
  #undef COMPUTE
}

// ---- reduce split-K partials -> T1 bf16 (row-major + transposed) ------------
__global__ void reduce_t1() {
  __shared__ unsigned short tile[16][136];
  int r0 = blockIdx.x * 16;
  int t = threadIdx.x;
#pragma unroll
  for (int e = 0; e < 2; e++) {
    int linear = e * 1024 + t * 4;
    int r = linear >> 7, c = linear & 127;
    float4_t s = (float4_t){0.f, 0.f, 0.f, 0.f};
#pragma unroll
    for (int p = 0; p < SPLITK; p++)
      s += *(const float4_t*)(g_part + (size_t)p * NR * C + (size_t)(r0 + r) * C + c);
    ushort4_t h; h[0]=f2bf(s[0]); h[1]=f2bf(s[1]); h[2]=f2bf(s[2]); h[3]=f2bf(s[3]);
    *(ushort4_t*)(g_T1b + (size_t)(r0 + r) * C + c) = h;
    *(ushort4_t*)(&tile[r][c]) = h;
  }
  __syncthreads();
  int c = t >> 1, half = t & 1;
  short8 h;
#pragma unroll
  for (int j = 0; j < 8; j++) h[j] = (short)tile[half * 8 + j][c];
  *(short8*)(g_T1bT + (size_t)c * NR + r0 + half * 8) = h;   // 16B store
}

// ---- epilogue: reduce U partials, T2 = 2U - x, out = sum_j T_j W_j^T --------
__global__ __launch_bounds__(256) void epilogue(const float* __restrict__ x,
                                                float* __restrict__ out) {
  __shared__ unsigned short t2[32][136];
  int r0 = blockIdx.x * 32;
  int t = threadIdx.x;
#pragma unroll
  for (int e = 0; e < 4; e++) {
    int linear = e * 1024 + t * 4;
    int r = linear >> 7, c = linear & 127;
    float4_t s = (float4_t){0.f, 0.f, 0.f, 0.f};
#pragma unroll
    for (int p = 0; p < SPLITK; p++)
      s += *(const float4_t*)(g_part + (size_t)p * NR * C + (size_t)(r0 + r) * C + c);
    float4_t xv = *(const float4_t*)(x + (size_t)(r0 + r) * C + c);
    float4_t t2v = 2.0f * s - xv;
    ushort4_t h; h[0]=f2bf(t2v[0]); h[1]=f2bf(t2v[1]); h[2]=f2bf(t2v[2]); h[3]=f2bf(t2v[3]);
    *(ushort4_t*)(&t2[r][c]) = h;
  }
  __syncthreads();

  int wave = t >> 6, lane = t & 63, l15 = lane & 15, lq = lane >> 4;
  int mf = wave & 1, nh = wave >> 1;
  int m0r = r0 + mf * 16;
  float4_t acc[4];
#pragma unroll
  for (int ni = 0; ni < 4; ni++) acc[ni] = (float4_t){0.f, 0.f, 0.f, 0.f};

#pragma unroll
  for (int ks = 0; ks < 4; ks++) {
    int k0 = ks * 32 + lq * 8;
    const float* px = x + (size_t)(m0r + l15) * C + k0;
    float4_t f0 = *(const float4_t*)px;
    float4_t f1 = *(const float4_t*)(px + 4);
    short8 a0 = cvt8(f0, f1);
    short8 a1 = *(const short8*)(g_T1b + (size_t)(m0r + l15) * C + k0);
    short8 a2 = *(const short8*)(&t2[mf * 16 + l15][k0]);
#pragma unroll
    for (int ni = 0; ni < 4; ni++) {
      int n = nh * 64 + ni * 16 + l15;
      const unsigned short* pw = g_Wb + (size_t)n * C + k0;
      short8 w0 = *(const short8*)(pw);
      short8 w1 = *(const short8*)(pw + C * C);
      short8 w2 = *(const short8*)(pw + 2 * C * C);
      acc[ni] = __builtin_amdgcn_mfma_f32_16x16x32_bf16(a0, w0, acc[ni], 0, 0, 0);
      acc[ni] = __builtin_amdgcn_mfma_f32_16x16x32_bf16(a1, w1, acc[ni], 0, 0, 0);
      acc[ni] = __builtin_amdgcn_mfma_f32_16x16x32_bf16(a2, w2, acc[ni], 0, 0, 0);
    }
  }
#pragma unroll
  for (int ni = 0; ni < 4; ni++)
#pragma unroll
    for (int r = 0; r < 4; r++)
      out[(size_t)(m0r + lq * 4 + r) * C + nh * 64 + ni * 16 + l15] = acc[ni][r];
}

extern "C" void kernel_launch(void* const* d_in, const int* in_sizes, int n_in,
                              void* d_out, int out_size, void* d_ws, size_t ws_size,
                              hipStream_t stream) {
  const float* x = (const float*)d_in[0];   // [8192][128]
  const float* L = (const float*)d_in[1];   // [8192][8192]
  const float* W = (const float*)d_in[2];   // [3][128][128]
  float* out = (float*)d_out;               // [8192][128]

  cvt_w<<<48, 256, 0, stream>>>(W);
  transpose_x<<<dim3(128, 2), 256, 0, stream>>>(x);
  gemm_t1<<<dim3(128, SPLITK), 256, 0, stream>>>(L);   // T1 partials + pack L->bf16
  reduce_t1<<<512, 256, 0, stream>>>();                // -> T1b, T1bT
  gemm_u<<<dim3(128, SPLITK), 256, 0, stream>>>();     // U partials (packed A)
  epilogue<<<256, 256, 0, stream>>>(x, out);           // T2 + three W-GEMMs
}

// Round 9
// 487.131 us; speedup vs baseline: 1.3869x; 1.0228x over previous
//
#include <hip/hip_runtime.h>

typedef __attribute__((ext_vector_type(8))) short short8;
typedef __attribute__((ext_vector_type(4))) float float4_t;
typedef __attribute__((ext_vector_type(4))) unsigned short ushort4_t;

#define NR 8192
#define C 128
#define SPLITK 4
#define KCHUNK (NR / SPLITK)   // 2048
#define BK 64
#define STEPS (KCHUNK / BK)    // 32

// Static device scratch (fully rewritten each call; no reliance on ws_size).
__device__ unsigned short g_Lb[(size_t)NR * NR];    // packed bf16 L: [mb][kq][r][8] (128 MB)
__device__ unsigned short g_xbT[(size_t)C * NR];    // xbT[c][n] = bf16(x[n][c])
__device__ unsigned short g_T1b[(size_t)NR * C];    // row-major bf16 T1
__device__ unsigned short g_T1bT[(size_t)C * NR];   // T1bT[c][n] = bf16(T1[n][c])
__device__ unsigned short g_Wb[3 * C * C];          // bf16 W
__device__ float g_part[(size_t)SPLITK * NR * C];   // split-K partials (16 MB)

__device__ __forceinline__ unsigned short f2bf(float f) {
  union { float f; unsigned u; } v; v.f = f;
  unsigned r = v.u + 0x7fffu + ((v.u >> 16) & 1u);  // RNE
  return (unsigned short)(r >> 16);
}
__device__ __forceinline__ unsigned pk2(float a, float b) {
  union { float f; unsigned u; } x, y; x.f = a; y.f = b;
  unsigned ra = x.u + 0x7fffu + ((x.u >> 16) & 1u);
  unsigned rb = y.u + 0x7fffu + ((y.u >> 16) & 1u);
  return (ra >> 16) | (rb & 0xffff0000u);
}
__device__ __forceinline__ short8 cvt8(float4_t f0, float4_t f1) {
  union { unsigned u[4]; short8 s; } r;
  r.u[0] = pk2(f0[0], f0[1]); r.u[1] = pk2(f0[2], f0[3]);
  r.u[2] = pk2(f1[0], f1[1]); r.u[3] = pk2(f1[2], f1[3]);
  return r.s;
}

typedef __attribute__((address_space(3))) unsigned lds_uint;
typedef const __attribute__((address_space(1))) unsigned glob_uint;
__device__ __forceinline__ void gload_lds16(const void* g, void* l) {
  __builtin_amdgcn_global_load_lds((glob_uint*)g, (lds_uint*)l, 16, 0, 0);
}

// ---- tiny: W fp32 -> bf16 ---------------------------------------------------
__global__ void cvt_w(const float* __restrict__ W) {
  int i = (blockIdx.x * 256 + threadIdx.x) * 4;
  float4_t v = *(const float4_t*)(W + i);
  ushort4_t h; h[0]=f2bf(v[0]); h[1]=f2bf(v[1]); h[2]=f2bf(v[2]); h[3]=f2bf(v[3]);
  *(ushort4_t*)(g_Wb + i) = h;
}

// ---- pack L: fp32 row-major -> bf16 [mb][kq][r][8] --------------------------
// Block (mb, y): rows mb*64..+63, cols y*512..+511. Reads are full-width row
// segments (2 KB per row visit -> page-friendly: measured 1.78 TB/s when the
// gemm reads 256 B/row/step directly; streaming layout avoids that). Writes
// one contiguous 64 KB run per block.
__global__ __launch_bounds__(256) void pack_l(const float* __restrict__ L) {
  __shared__ __attribute__((aligned(16))) unsigned short tile[64][520];
  int mb = blockIdx.x;   // 0..127
  int y  = blockIdx.y;   // 0..15
  int t = threadIdx.x;
#pragma unroll
  for (int it = 0; it < 32; it++) {
    int idx = it * 256 + t;        // f4 index 0..8191
    int row = idx >> 7;            // local row 0..63
    int c4  = idx & 127;           // f4 within row
    float4_t v = *(const float4_t*)(L + (size_t)(mb * 64 + row) * NR + y * 512 + c4 * 4);
    ushort4_t h; h[0]=f2bf(v[0]); h[1]=f2bf(v[1]); h[2]=f2bf(v[2]); h[3]=f2bf(v[3]);
    *(ushort4_t*)(&tile[row][c4 * 4]) = h;
  }
  __syncthreads();
  // unit u = kql*64 + r  (kql = local kq 0..63, r = local row 0..63)
  unsigned short* dst = g_Lb + (size_t)(mb * 1024 + y * 64) * 512;  // *64 rows *8 elems
#pragma unroll
  for (int j = 0; j < 16; j++) {
    int u = j * 256 + t;
    int kql = u >> 6, r = u & 63;
    short8 h = *(const short8*)(&tile[r][kql * 8]);   // contiguous 16B in LDS row
    *(short8*)(dst + (size_t)u * 8) = h;              // per-wave contiguous 1KB
  }
}

// ---- x [8192][128] fp32 -> xbT [128][8192] bf16 -----------------------------
__global__ void transpose_x(const float* __restrict__ x) {
  __shared__ unsigned short xt[64][72];
  int r0 = blockIdx.x * 64;
  int c0 = blockIdx.y * 64;
  int t = threadIdx.x;
  int rr = t >> 4;
  int cc = (t & 15) * 4;
#pragma unroll
  for (int i = 0; i < 4; i++) {
    int row = i * 16 + rr;
    float4_t v = *(const float4_t*)(x + (size_t)(r0 + row) * C + c0 + cc);
    ushort4_t h; h[0]=f2bf(v[0]); h[1]=f2bf(v[1]); h[2]=f2bf(v[2]); h[3]=f2bf(v[3]);
    *(ushort4_t*)(&xt[row][cc]) = h;
  }
  __syncthreads();
  int c = t >> 2, q = t & 3;   // c 0..63, q: 16-row group
  unsigned short* dst = g_xbT + (size_t)(c0 + c) * NR + r0 + q * 16;
#pragma unroll
  for (int seg = 0; seg < 2; seg++) {
    short8 h;
#pragma unroll
    for (int j = 0; j < 8; j++) h[j] = (short)xt[q * 16 + seg * 8 + j][c];
    *(short8*)(dst + seg * 8) = h;   // 16B stores
  }
}

// ---- GEMM: part = Lb(bf16 packed) @ B ; BM=64, BN=128, BK=64 ----------------
// A is the packed layout: each step's 8 KB A-tile is one contiguous burst.
// TRIPLE-buffered LDS (3x24 KB), prefetch depth 2: steady-state vmcnt(12)
// keeps 18 loads (48 KB/block) in flight ACROSS every barrier, so the HBM
// queue never drains at the per-step sync (gemm_t1 counters showed the
// 2-deep variant latency-bound: MfmaUtil 3.9 / VALUBusy 6.3 / HBM 22%).
// which==0: BT=g_xbT (T1); which==1: BT=g_T1bT (U).
__global__ __launch_bounds__(256, 2) void gemm_cheb(int which) {
  const unsigned short* __restrict__ BT = which ? g_T1bT : g_xbT;
  __shared__ __attribute__((aligned(16))) unsigned short As[3][64 * BK];   // 3x8 KB
  __shared__ __attribute__((aligned(16))) unsigned short Bs[3][128 * BK];  // 3x16 KB
  int tid = threadIdx.x;
  int wave = tid >> 6, lane = tid & 63;
  int l15 = lane & 15, lq = lane >> 4;
  int m0 = blockIdx.x * 64;
  int kb = blockIdx.y * KCHUNK;

  // A staging: 8 KB/step = 512 units of 16B; unit = kq_local*64 + r.
  const unsigned short* pA[2];
  size_t abase = (size_t)(blockIdx.x * 1024 + blockIdx.y * (KCHUNK / 8)) * 512;
#pragma unroll
  for (int i = 0; i < 2; i++)
    pA[i] = g_Lb + abase + (size_t)((wave * 2 + i) * 64 + lane) * 8;

  // B staging: 128 n x 64 bf16 = 16KB = 8 units of 16B per row (XOR-swizzled).
  const unsigned short* pB[4];
#pragma unroll
  for (int i = 0; i < 4; i++) {
    int U = (wave * 4 + i) * 64 + lane;   // 0..1023
    int n = U >> 3, p = U & 7;
    pB[i] = BT + (size_t)n * NR + kb + ((p ^ (n & 7)) << 3);
  }

  float4_t acc[8];
#pragma unroll
  for (int ni = 0; ni < 8; ni++) acc[ni] = (float4_t){0.f, 0.f, 0.f, 0.f};

  #define ISSUE(buf)                                                         \
    do {                                                                     \
      _Pragma("unroll")                                                      \
      for (int i = 0; i < 2; i++)                                            \
        gload_lds16(pA[i], (char*)&As[buf][0] + (wave * 2 + i) * 1024);      \
      _Pragma("unroll")                                                      \
      for (int i = 0; i < 4; i++)                                            \
        gload_lds16(pB[i], (char*)&Bs[buf][0] + (wave * 4 + i) * 1024);      \
      _Pragma("unroll")                                                      \
      for (int i = 0; i < 2; i++) pA[i] += 8 * 64 * 8;                       \
      _Pragma("unroll")                                                      \
      for (int i = 0; i < 4; i++) pB[i] += BK;                               \
    } while (0)

  #define COMPUTE(buf)                                                       \
    do {                                                                     \
      _Pragma("unroll")                                                      \
      for (int ki = 0; ki < 2; ki++) {                                       \
        int row = wave * 16 + l15;                                           \
        short8 a = *(const short8*)((const char*)&As[buf][0] +               \
                                    ((((ki * 4 + lq) << 6) + row) << 4));    \
        _Pragma("unroll")                                                    \
        for (int ni = 0; ni < 8; ni++) {                                     \
          int n = ni * 16 + l15;                                             \
          int pb = ((ki << 2) | lq) ^ (n & 7);                               \
          short8 b = *(const short8*)((const char*)&Bs[buf][0] + n * 128 + pb * 16);             \
          acc[ni] = __builtin_amdgcn_mfma_f32_16x16x32_bf16(a, b, acc[ni], 0, 0, 0);             \
        }                                                                    \
      }                                                                      \
    } while (0)

  ISSUE(0);
  ISSUE(1);
  int p = 0;
  for (int step = 0; step < STEPS - 2; step++) {
    int nxt = p + 2; if (nxt >= 3) nxt -= 3;
    ISSUE(nxt);                                          // prefetch step+2
    // outstanding: 6 (step) + 6 (step+1) + 6 (step+2); wait step's only.
    asm volatile("s_waitcnt vmcnt(12)" ::: "memory");
    asm volatile("s_barrier" ::: "memory");              // everyone's are done
    COMPUTE(p);
    asm volatile("s_barrier" ::: "memory");              // buf p free to overwrite
    p = p + 1; if (p >= 3) p -= 3;
  }
  // step STEPS-2: outstanding 12; wait its 6.
  asm volatile("s_waitcnt vmcnt(6)" ::: "memory");
  asm volatile("s_barrier" ::: "memory");
  COMPUTE(p);
  p = p + 1; if (p >= 3) p -= 3;
  // step STEPS-1
  asm volatile("s_waitcnt vmcnt(0)" ::: "memory");
  asm volatile("s_barrier" ::: "memory");
  COMPUTE(p);

  float* po = g_part + (size_t)blockIdx.y * NR * C;
#pragma unroll
  for (int ni = 0; ni < 8; ni++)
#pragma unroll
    for (int r = 0; r < 4; r++)
      po[(size_t)(m0 + wave * 16 + lq * 4 + r) * C + ni * 16 + l15] = acc[ni][r];
  #undef ISSUE
  #undef COMPUTE
}

// ---- reduce split-K partials -> T1 bf16 (row-major + transposed) ------------
__global__ void reduce_t1() {
  __shared__ unsigned short tile[16][136];
  int r0 = blockIdx.x * 16;
  int t = threadIdx.x;
#pragma unroll
  for (int e = 0; e < 2; e++) {
    int linear = e * 1024 + t * 4;
    int r = linear >> 7, c = linear & 127;
    float4_t s = (float4_t){0.f, 0.f, 0.f, 0.f};
#pragma unroll
    for (int p = 0; p < SPLITK; p++)
      s += *(const float4_t*)(g_part + (size_t)p * NR * C + (size_t)(r0 + r) * C + c);
    ushort4_t h; h[0]=f2bf(s[0]); h[1]=f2bf(s[1]); h[2]=f2bf(s[2]); h[3]=f2bf(s[3]);
    *(ushort4_t*)(g_T1b + (size_t)(r0 + r) * C + c) = h;
    *(ushort4_t*)(&tile[r][c]) = h;
  }
  __syncthreads();
  int c = t >> 1, half = t & 1;
  short8 h;
#pragma unroll
  for (int j = 0; j < 8; j++) h[j] = (short)tile[half * 8 + j][c];
  *(short8*)(g_T1bT + (size_t)c * NR + r0 + half * 8) = h;   // 16B store
}

// ---- epilogue: reduce U partials, T2 = 2U - x, out = sum_j T_j W_j^T --------
__global__ __launch_bounds__(256) void epilogue(const float* __restrict__ x,
                                                float* __restrict__ out) {
  __shared__ unsigned short t2[32][136];
  int r0 = blockIdx.x * 32;
  int t = threadIdx.x;
#pragma unroll
  for (int e = 0; e < 4; e++) {
    int linear = e * 1024 + t * 4;
    int r = linear >> 7, c = linear & 127;
    float4_t s = (float4_t){0.f, 0.f, 0.f, 0.f};
#pragma unroll
    for (int p = 0; p < SPLITK; p++)
      s += *(const float4_t*)(g_part + (size_t)p * NR * C + (size_t)(r0 + r) * C + c);
    float4_t xv = *(const float4_t*)(x + (size_t)(r0 + r) * C + c);
    float4_t t2v = 2.0f * s - xv;
    ushort4_t h; h[0]=f2bf(t2v[0]); h[1]=f2bf(t2v[1]); h[2]=f2bf(t2v[2]); h[3]=f2bf(t2v[3]);
    *(ushort4_t*)(&t2[r][c]) = h;
  }
  __syncthreads();

  int wave = t >> 6, lane = t & 63, l15 = lane & 15, lq = lane >> 4;
  int mf = wave & 1, nh = wave >> 1;
  int m0r = r0 + mf * 16;
  float4_t acc[4];
#pragma unroll
  for (int ni = 0; ni < 4; ni++) acc[ni] = (float4_t){0.f, 0.f, 0.f, 0.f};

#pragma unroll
  for (int ks = 0; ks < 4; ks++) {
    int k0 = ks * 32 + lq * 8;
    const float* px = x + (size_t)(m0r + l15) * C + k0;
    float4_t f0 = *(const float4_t*)px;
    float4_t f1 = *(const float4_t*)(px + 4);
    short8 a0 = cvt8(f0, f1);
    short8 a1 = *(const short8*)(g_T1b + (size_t)(m0r + l15) * C + k0);
    short8 a2 = *(const short8*)(&t2[mf * 16 + l15][k0]);
#pragma unroll
    for (int ni = 0; ni < 4; ni++) {
      int n = nh * 64 + ni * 16 + l15;
      const unsigned short* pw = g_Wb + (size_t)n * C + k0;
      short8 w0 = *(const short8*)(pw);
      short8 w1 = *(const short8*)(pw + C * C);
      short8 w2 = *(const short8*)(pw + 2 * C * C);
      acc[ni] = __builtin_amdgcn_mfma_f32_16x16x32_bf16(a0, w0, acc[ni], 0, 0, 0);
      acc[ni] = __builtin_amdgcn_mfma_f32_16x16x32_bf16(a1, w1, acc[ni], 0, 0, 0);
      acc[ni] = __builtin_amdgcn_mfma_f32_16x16x32_bf16(a2, w2, acc[ni], 0, 0, 0);
    }
  }
#pragma unroll
  for (int ni = 0; ni < 4; ni++)
#pragma unroll
    for (int r = 0; r < 4; r++)
      out[(size_t)(m0r + lq * 4 + r) * C + nh * 64 + ni * 16 + l15] = acc[ni][r];
}

extern "C" void kernel_launch(void* const* d_in, const int* in_sizes, int n_in,
                              void* d_out, int out_size, void* d_ws, size_t ws_size,
                              hipStream_t stream) {
  const float* x = (const float*)d_in[0];   // [8192][128]
  const float* L = (const float*)d_in[1];   // [8192][8192]
  const float* W = (const float*)d_in[2];   // [3][128][128]
  float* out = (float*)d_out;               // [8192][128]

  cvt_w<<<48, 256, 0, stream>>>(W);
  transpose_x<<<dim3(128, 2), 256, 0, stream>>>(x);
  pack_l<<<dim3(128, 16), 256, 0, stream>>>(L);            // L -> bf16 packed
  gemm_cheb<<<dim3(128, SPLITK), 256, 0, stream>>>(0);     // T1 partials
  reduce_t1<<<512, 256, 0, stream>>>();                    // -> T1b, T1bT
  gemm_cheb<<<dim3(128, SPLITK), 256, 0, stream>>>(1);     // U partials
  epilogue<<<256, 256, 0, stream>>>(x, out);               // T2 + three W-GEMMs
}